// Round 15
// baseline (1141.118 us; speedup 1.0000x reference)
//
#include <hip/hip_runtime.h>

#define BATCH 8
#define T 4096
#define NCH 256
#define NCTX 80
#define NLAYERS 8

typedef unsigned short u16;
typedef __attribute__((ext_vector_type(8))) short short8;
typedef __attribute__((ext_vector_type(4))) short short4v;
typedef __attribute__((ext_vector_type(4))) float float4v;

__device__ __forceinline__ float b2f(u16 u) {
    unsigned v = ((unsigned)u) << 16;
    float f;
    __builtin_memcpy(&f, &v, 4);
    return f;
}
__device__ __forceinline__ u16 f2b(float f) {
    unsigned v;
    __builtin_memcpy(&v, &f, 4);
    unsigned r = v + 0x7FFFu + ((v >> 16) & 1u);
    return (u16)(r >> 16);
}

typedef const __attribute__((address_space(1))) unsigned int* gp1;
typedef __attribute__((address_space(3))) unsigned int* lp3;
__device__ __forceinline__ void gl_lds16(const u16* g, u16* l) {
    __builtin_amdgcn_global_load_lds((gp1)g, (lp3)l, 16, 0, 0);
}

// Inputs are fp32 (established rounds 2/3). B-operand weights are pre-swizzled
// into MFMA fragment order (tile = 64 lanes x 8 bf16 = 1KB) so the K-loop
// streams them global->register with fully-coalesced dwordx4 loads, bypassing
// LDS (round 14 showed the kernel LDS-bandwidth-bound: 144KB/chunk through a
// 128 B/cyc port vs 620 cyc of MFMA).

// ---------------- convert fp32 -> bf16 (biases) ----------------
__global__ void cvt_kernel(const float* __restrict__ src, u16* __restrict__ dst, int n) {
    int i = blockIdx.x * 256 + threadIdx.x;
    if (i < n) dst[i] = f2b(src[i]);
}

// ---------------- build Wf: conv weights in fragment order ----------------
// Wf[(l*2+h)*27+s][tile nt 0..15][lane 0..63][j 0..7], tile covers n=h*256+nt*16+(lane&15),
// k=s*32+(lane>>4)*8+j of the im2col matrix (3 taps | cond | bias | pad).
__global__ void prep_wf(const float* __restrict__ in_w, const float* __restrict__ in_b,
                        const float* __restrict__ cond_w, const float* __restrict__ cond_b,
                        u16* __restrict__ Wf) {
    int bid = blockIdx.x;          // (l*2+h)*27 + s, 432 blocks
    int s = bid % 27;
    int lh = bid / 27;
    int h = lh & 1, l = lh >> 1;
    const int tid = threadIdx.x;
    for (int it = 0; it < 32; it++) {
        int e = it * 256 + tid;    // 0..8191
        int nt = e >> 9;
        int r = e & 511;
        int lane = r >> 3, j = r & 7;
        int n = h * 256 + nt * 16 + (lane & 15);
        int k = s * 32 + (lane >> 4) * 8 + j;
        int row = l * 512 + n;
        float v;
        if (k < 256)       v = in_w[((size_t)row * 256 + k) * 3];
        else if (k < 512)  v = in_w[((size_t)row * 256 + (k - 256)) * 3 + 1];
        else if (k < 768)  v = in_w[((size_t)row * 256 + (k - 512)) * 3 + 2];
        else if (k < 848)  v = cond_w[(size_t)row * 80 + (k - 768)];
        else if (k == 848) v = in_b[row] + cond_b[row];
        else               v = 0.f;
        Wf[(size_t)bid * 8192 + e] = f2b(v);
    }
}

// ---------------- build Rf: rs weights in fragment order ----------------
__global__ void prep_rf(const float* __restrict__ rs_w, u16* __restrict__ Rf) {
    int bid = blockIdx.x;          // (l*2+h)*8 + s, 128 blocks
    int s = bid & 7;
    int lh = bid >> 3;
    int h = lh & 1, l = lh >> 1;
    const int tid = threadIdx.x;
    for (int it = 0; it < 32; it++) {
        int e = it * 256 + tid;
        int nt = e >> 9;
        int r = e & 511;
        int lane = r >> 3, j = r & 7;
        int n = h * 256 + nt * 16 + (lane & 15);
        int k = s * 32 + (lane >> 4) * 8 + j;
        float v = rs_w[((size_t)(l * 512 + n)) * 256 + k];
        Rf[(size_t)bid * 8192 + e] = f2b(v);
    }
}

// ---------------- transpose context -> ctx_t [B][T][96] ----------------
__global__ void prep_ctx(const float* __restrict__ ctx, u16* __restrict__ ctxt) {
    __shared__ float sm[80][65];
    const int tid = threadIdx.x;
    const int b = blockIdx.y, t0 = blockIdx.x * 64;
    for (int it = 0; it < 20; it++) {
        int e = it * 256 + tid;
        int j = e >> 6, tt = e & 63;
        sm[j][tt] = ctx[((size_t)b * 80 + j) * T + t0 + tt];
    }
    __syncthreads();
    for (int it = 0; it < 24; it++) {
        int e = it * 256 + tid;
        int r = e / 96, c = e - r * 96;
        float v = (c < 80) ? sm[c][r] : (c == 80 ? 1.f : 0.f);
        ctxt[((size_t)b * T + t0 + r) * 96 + c] = f2b(v);
    }
}

// ---------------- start conv (4 -> 256, 1x1) -> x_t [B][T][256] ----------------
__global__ void start_kernel(const float* __restrict__ fc, const float* __restrict__ w,
                             const float* __restrict__ bias, u16* __restrict__ xt) {
    __shared__ float fsm[4][64];
    __shared__ float wsm[1024];
    __shared__ float bsm[256];
    const int tid = threadIdx.x;
    const int b = blockIdx.y, t0 = blockIdx.x * 64;
    fsm[tid >> 6][tid & 63] = fc[((size_t)b * 8 + (tid >> 6)) * T + t0 + (tid & 63)];
    for (int it = 0; it < 4; it++) wsm[it * 256 + tid] = w[it * 256 + tid];
    bsm[tid] = bias[tid];
    __syncthreads();
    for (int r = 0; r < 64; r++) {
        int c = tid;
        float a = bsm[c];
#pragma unroll
        for (int k = 0; k < 4; k++) a += wsm[c * 4 + k] * fsm[k][r];
        xt[((size_t)b * T + t0 + r) * 256 + c] = f2b(a);
    }
}

// ================= layer conv: dilated conv+cond GEMM + gate -> acts =================
// grid (32, 8), 512 threads. M=128, N=512, K=864 = 27 K-steps of 32.
// A (activations) via LDS triple-buffer + DMA; B (weights) global->register
// fragments. One barrier per K-step; both gate halves per step (A reused).
__global__ __launch_bounds__(512, 1) void layer_conv(
    const u16* __restrict__ x, const u16* __restrict__ Wf, const u16* __restrict__ ctxt,
    u16* __restrict__ acts, int layer, int dil) {
    __shared__ u16 lds[12288];  // A: 3 x 4096 u16 (24.5 KB)
    const int tid = threadIdx.x;
    const int w = tid >> 6, lane = tid & 63;
    const int l15 = lane & 15, quad = lane >> 4;
    const int iw = w >> 1, jc = w & 1;  // wave: t-rows 32*iw, cols 128*jc (per half)
    const int b = blockIdx.y, t0 = blockIdx.x * 128;
    const int lrow = lane >> 2;
    const int lsw = (((lane & 3) ^ ((lane >> 3) & 3)) * 8);  // A writer swizzle
    const int rq = ((quad ^ ((l15 >> 1) & 3)) * 8);          // A reader swizzle

    const u16* xb = x + (size_t)b * T * 256;
    const u16* cb = ctxt + (size_t)b * T * 96;
    const u16* wbT = Wf + ((size_t)(layer * 2 + 0) * 27) * 8192 + (jc * 8) * 512 + lane * 8;
    const u16* wbS = Wf + ((size_t)(layer * 2 + 1) * 27) * 8192 + (jc * 8) * 512 + lane * 8;

    float4v acc0[2][8], acc1[2][8];  // acc0 = tanh half, acc1 = sigm half
#pragma unroll
    for (int m = 0; m < 2; m++)
#pragma unroll
        for (int jj = 0; jj < 8; jj++) {
            acc0[m][jj] = (float4v){0.f, 0.f, 0.f, 0.f};
            acc1[m][jj] = (float4v){0.f, 0.f, 0.f, 0.f};
        }

    auto stageA = [&](int s, int abuf) {  // 128 rows x 32 u16; wave w: rows 16w..16w+16
        u16* dst = &lds[abuf * 4096 + w * 512];
        if (s < 24) {
            int seg = s >> 3, cs = s & 7;
            int tb = t0 + 16 * w + (seg - 1) * dil;
            if (tb >= 0 && tb + 16 <= T) {
                gl_lds16(xb + (size_t)(tb + lrow) * 256 + cs * 32 + lsw, dst);
            } else {  // boundary tile: masked manual path (rare)
                int t = tb + lrow;
                short8 av = (short8){0, 0, 0, 0, 0, 0, 0, 0};
                if (t >= 0 && t < T)
                    av = *(const short8*)(xb + (size_t)t * 256 + cs * 32 + lsw);
                *(short4v*)&dst[lane * 8] = __builtin_shufflevector(av, av, 0, 1, 2, 3);
                *(short4v*)&dst[lane * 8 + 4] = __builtin_shufflevector(av, av, 4, 5, 6, 7);
            }
        } else {
            gl_lds16(cb + (size_t)(t0 + 16 * w + lrow) * 96 + (s - 24) * 32 + lsw, dst);
        }
    };

    stageA(0, 0);
    stageA(1, 1);
    __syncthreads();
#pragma unroll 1
    for (int s = 0; s < 27; s++) {
        const u16* bA = &lds[(s % 3) * 4096];
        short8 af0 = *(const short8*)&bA[(32 * iw + l15) * 32 + rq];
        short8 af1 = *(const short8*)&bA[(32 * iw + 16 + l15) * 32 + rq];
        if (s + 2 < 27) stageA(s + 2, (s + 2) % 3);
        short8 bfT[8], bfS[8];
        const u16* wT = wbT + (size_t)s * 8192;
        const u16* wS = wbS + (size_t)s * 8192;
#pragma unroll
        for (int jj = 0; jj < 8; jj++) bfT[jj] = *(const short8*)(wT + jj * 512);
#pragma unroll
        for (int jj = 0; jj < 8; jj++) bfS[jj] = *(const short8*)(wS + jj * 512);
#pragma unroll
        for (int jj = 0; jj < 8; jj++) {
            acc0[0][jj] = __builtin_amdgcn_mfma_f32_16x16x32_bf16(af0, bfT[jj], acc0[0][jj], 0, 0, 0);
            acc0[1][jj] = __builtin_amdgcn_mfma_f32_16x16x32_bf16(af1, bfT[jj], acc0[1][jj], 0, 0, 0);
        }
#pragma unroll
        for (int jj = 0; jj < 8; jj++) {
            acc1[0][jj] = __builtin_amdgcn_mfma_f32_16x16x32_bf16(af0, bfS[jj], acc1[0][jj], 0, 0, 0);
            acc1[1][jj] = __builtin_amdgcn_mfma_f32_16x16x32_bf16(af1, bfS[jj], acc1[1][jj], 0, 0, 0);
        }
        __syncthreads();
    }

    // gate + store acts[b][t][o]
    u16* ab = acts + (size_t)b * T * 256;
#pragma unroll
    for (int m = 0; m < 2; m++)
#pragma unroll
        for (int jj = 0; jj < 8; jj++) {
            int o = 128 * jc + 16 * jj + l15;
#pragma unroll
            for (int r = 0; r < 4; r++) {
                int t = t0 + 32 * iw + 16 * m + quad * 4 + r;
                float at = acc0[m][jj][r], as = acc1[m][jj][r];
                float e2 = __expf(2.f * at);
                float th = 1.f - 2.f / (e2 + 1.f);
                float sg = 1.f / (1.f + __expf(-as));
                ab[(size_t)t * 256 + o] = f2b(th * sg);
            }
        }
}

// ================= layer rs: 1x1 conv (K=256) + residual/skip update =================
__global__ __launch_bounds__(512, 1) void layer_rs(
    const u16* __restrict__ acts, u16* __restrict__ x, const u16* __restrict__ Rf,
    const u16* __restrict__ rsb, u16* __restrict__ oacc, int layer, int first, int last) {
    __shared__ u16 lds[12288];
    const int tid = threadIdx.x;
    const int w = tid >> 6, lane = tid & 63;
    const int l15 = lane & 15, quad = lane >> 4;
    const int iw = w >> 1, jc = w & 1;
    const int b = blockIdx.y, t0 = blockIdx.x * 128;
    const int lrow = lane >> 2;
    const int lsw = (((lane & 3) ^ ((lane >> 3) & 3)) * 8);
    const int rq = ((quad ^ ((l15 >> 1) & 3)) * 8);

    const u16* ab = acts + (size_t)b * T * 256;
    const u16* wbT = Rf + ((size_t)(layer * 2 + 0) * 8) * 8192 + (jc * 8) * 512 + lane * 8;
    const u16* wbS = Rf + ((size_t)(layer * 2 + 1) * 8) * 8192 + (jc * 8) * 512 + lane * 8;

    float4v acc0[2][8], acc1[2][8];
#pragma unroll
    for (int m = 0; m < 2; m++)
#pragma unroll
        for (int jj = 0; jj < 8; jj++) {
            acc0[m][jj] = (float4v){0.f, 0.f, 0.f, 0.f};
            acc1[m][jj] = (float4v){0.f, 0.f, 0.f, 0.f};
        }

    auto stageA = [&](int s, int abuf) {
        gl_lds16(ab + (size_t)(t0 + 16 * w + lrow) * 256 + s * 32 + lsw,
                 &lds[abuf * 4096 + w * 512]);
    };

    stageA(0, 0);
    stageA(1, 1);
    __syncthreads();
#pragma unroll 1
    for (int s = 0; s < 8; s++) {
        const u16* bA = &lds[(s % 3) * 4096];
        short8 af0 = *(const short8*)&bA[(32 * iw + l15) * 32 + rq];
        short8 af1 = *(const short8*)&bA[(32 * iw + 16 + l15) * 32 + rq];
        if (s + 2 < 8) stageA(s + 2, (s + 2) % 3);
        short8 bfT[8], bfS[8];
        const u16* wT = wbT + (size_t)s * 8192;
        const u16* wS = wbS + (size_t)s * 8192;
#pragma unroll
        for (int jj = 0; jj < 8; jj++) bfT[jj] = *(const short8*)(wT + jj * 512);
#pragma unroll
        for (int jj = 0; jj < 8; jj++) bfS[jj] = *(const short8*)(wS + jj * 512);
#pragma unroll
        for (int jj = 0; jj < 8; jj++) {
            acc0[0][jj] = __builtin_amdgcn_mfma_f32_16x16x32_bf16(af0, bfT[jj], acc0[0][jj], 0, 0, 0);
            acc0[1][jj] = __builtin_amdgcn_mfma_f32_16x16x32_bf16(af1, bfT[jj], acc0[1][jj], 0, 0, 0);
        }
#pragma unroll
        for (int jj = 0; jj < 8; jj++) {
            acc1[0][jj] = __builtin_amdgcn_mfma_f32_16x16x32_bf16(af0, bfS[jj], acc1[0][jj], 0, 0, 0);
            acc1[1][jj] = __builtin_amdgcn_mfma_f32_16x16x32_bf16(af1, bfS[jj], acc1[1][jj], 0, 0, 0);
        }
        __syncthreads();
    }

    u16* xv = x + (size_t)b * T * 256;
    u16* oo = oacc + (size_t)b * T * 256;
#pragma unroll
    for (int m = 0; m < 2; m++)
#pragma unroll
        for (int jj = 0; jj < 8; jj++) {
            int o = 128 * jc + 16 * jj + l15;
            float b0 = b2f(rsb[layer * 512 + o]);
            float b1 = b2f(rsb[layer * 512 + 256 + o]);
#pragma unroll
            for (int r = 0; r < 4; r++) {
                int t = t0 + 32 * iw + 16 * m + quad * 4 + r;
                size_t idx = (size_t)t * 256 + o;
                float v0 = acc0[m][jj][r] + b0;
                if (last) {
                    oo[idx] = f2b(b2f(oo[idx]) + v0);  // last: rs[:256] -> skip
                } else {
                    xv[idx] = f2b(b2f(xv[idx]) + v0);  // residual (in place, own tile)
                    float v1 = acc1[m][jj][r] + b1;
                    oo[idx] = first ? f2b(v1) : f2b(b2f(oo[idx]) + v1);
                }
            }
        }
}

// ---------------- end conv (256 -> 8) + affine + output assembly (fp32 out) ----------------
__global__ void end_kernel(const u16* __restrict__ oacc, const float* __restrict__ w_end,
                           const float* __restrict__ b_end, const float* __restrict__ fc,
                           float* __restrict__ out) {
    __shared__ float wsm[2048];
    __shared__ float bsm[8];
    const int tid = threadIdx.x;
    for (int it = 0; it < 8; it++) wsm[it * 256 + tid] = w_end[it * 256 + tid];
    if (tid < 8) bsm[tid] = b_end[tid];
    __syncthreads();
    int gid = blockIdx.x * 256 + tid;  // 0..32767
    int b = gid >> 12, t = gid & 4095;
    float o8[8];
#pragma unroll
    for (int o = 0; o < 8; o++) o8[o] = bsm[o];
    const u16* orow = oacc + (size_t)(b * T + t) * 256;
    for (int c8 = 0; c8 < 32; c8++) {
        short8 v8 = *(const short8*)(orow + c8 * 8);
#pragma unroll
        for (int k = 0; k < 8; k++) {
            float v = b2f((u16)v8[k]);
            int c = c8 * 8 + k;
#pragma unroll
            for (int o = 0; o < 8; o++) o8[o] += wsm[o * 256 + c] * v;
        }
    }
    size_t ob8 = (size_t)b * 8 * T;
#pragma unroll
    for (int j = 0; j < 4; j++) {
        float f1v = fc[ob8 + (size_t)(4 + j) * T + t];
        float ls = o8[4 + j];
        float val = __expf(ls) * f1v + o8[j];
        out[ob8 + (size_t)j * T + t] = fc[ob8 + (size_t)j * T + t];  // f0 bit-exact
        out[ob8 + (size_t)(4 + j) * T + t] = val;
        out[(size_t)BATCH * 8 * T + ((size_t)b * 4 + j) * T + t] = ls;
    }
}

extern "C" void kernel_launch(void* const* d_in, const int* in_sizes, int n_in,
                              void* d_out, int out_size, void* d_ws, size_t ws_size,
                              hipStream_t stream) {
    const float* forecast = (const float*)d_in[0];
    const float* context  = (const float*)d_in[1];
    const float* start_w  = (const float*)d_in[2];
    const float* start_b  = (const float*)d_in[3];
    const float* cond_w   = (const float*)d_in[4];
    const float* cond_b   = (const float*)d_in[5];
    const float* in_w     = (const float*)d_in[6];
    const float* in_b     = (const float*)d_in[7];
    const float* rs_w     = (const float*)d_in[8];
    const float* rs_b     = (const float*)d_in[9];
    const float* end_w    = (const float*)d_in[10];
    const float* end_b    = (const float*)d_in[11];

    char* W = (char*)d_ws;
    u16* xA   = (u16*)(W + 0);                    // 16,777,216
    u16* oacc = (u16*)(W + 16777216);             // 16,777,216
    u16* acts = (u16*)(W + 33554432);             // 16,777,216
    u16* ctxt = (u16*)(W + 50331648);             //  6,291,456
    u16* Wf   = (u16*)(W + 56623104);             //  7,077,888 (432 * 8192 u16)
    u16* Rf   = (u16*)(W + 63700992);             //  2,097,152 (128 * 8192 u16)
    u16* rsb  = (u16*)(W + 65798144);             //      8,192  -> total ~62.8 MiB

    cvt_kernel<<<16, 256, 0, stream>>>(rs_b, rsb, 4096);
    prep_wf<<<432, 256, 0, stream>>>(in_w, in_b, cond_w, cond_b, Wf);
    prep_rf<<<128, 256, 0, stream>>>(rs_w, Rf);
    prep_ctx<<<dim3(64, BATCH), 256, 0, stream>>>(context, ctxt);
    start_kernel<<<dim3(64, BATCH), 256, 0, stream>>>(forecast, start_w, start_b, xA);

    const int dil[NLAYERS] = {1, 2, 4, 8, 16, 32, 64, 128};
    for (int l = 0; l < NLAYERS; l++) {
        layer_conv<<<dim3(32, BATCH), 512, 0, stream>>>(xA, Wf, ctxt, acts, l, dil[l]);
        layer_rs<<<dim3(32, BATCH), 512, 0, stream>>>(acts, xA, Rf, rsb, oacc, l,
                                                      l == 0, l == NLAYERS - 1);
    }

    end_kernel<<<128, 256, 0, stream>>>(oacc, end_w, end_b, forecast, (float*)d_out);
}